// Round 7
// baseline (918.492 us; speedup 1.0000x reference)
//
#include <hip/hip_runtime.h>
#include <stdint.h>

typedef unsigned short u16;
typedef __attribute__((ext_vector_type(8))) short short8;
typedef __attribute__((ext_vector_type(4))) float f32x4;

static __device__ __forceinline__ u16 bf16r(float f) {
  union { float f; uint32_t u; } c; c.f = f;
  uint32_t u = c.u;
  u += 0x7fffu + ((u >> 16) & 1u);
  return (u16)(u >> 16);
}

static constexpr int NB = 16, CIN = 256, COUT = 256, HW = 128, SDIM = 512;
static constexpr float SCALE = 1.0f / 48.0f;   // 1/sqrt(Cin*3*3)

// ---------------- K1: s[b][ci] = style[b,:] @ mod_w[ci,:] + mod_b[ci] ----------------
__global__ void k_style(const float* __restrict__ style, const float* __restrict__ mod_w,
                        const float* __restrict__ mod_b, float* __restrict__ s) {
  int b = blockIdx.x, ci = threadIdx.x;
  const float4* st = (const float4*)(style + (size_t)b * SDIM);
  const float4* mw = (const float4*)(mod_w + (size_t)ci * SDIM);
  float acc = 0.f;
  #pragma unroll 4
  for (int j = 0; j < SDIM / 4; ++j) {
    float4 a = st[j], w = mw[j];
    acc += a.x * w.x + a.y * w.y + a.z * w.z + a.w * w.w;
  }
  s[b * CIN + ci] = acc + mod_b[ci];
}

// ---------------- K2: modulated+demodulated weights -> bf16 Wb[b][kpos][co][ci] ------
__global__ void k_wmod(const float* __restrict__ weight, const float* __restrict__ s,
                       u16* __restrict__ Wb) {
  __shared__ float wld[CIN * 9];
  __shared__ float red[8];
  int bid = blockIdx.x;
  int b = bid >> 8, co = bid & 255;
  int t = threadIdx.x;
  const float* wsrc = weight + (size_t)co * (CIN * 9);
  for (int i = t; i < CIN * 9; i += 256) wld[i] = wsrc[i];
  __syncthreads();
  int ci = t;
  float sv = s[b * CIN + ci];
  float v[9];
  float sq = 0.f;
  #pragma unroll
  for (int k = 0; k < 9; ++k) {
    float w = SCALE * wld[ci * 9 + k] * sv;
    v[k] = w;
    sq += w * w;
  }
  #pragma unroll
  for (int off = 32; off; off >>= 1) sq += __shfl_down(sq, off);
  int lane = t & 63, wid = t >> 6;
  if (lane == 0) red[wid] = sq;
  __syncthreads();
  if (t == 0) red[4] = rsqrtf(red[0] + red[1] + red[2] + red[3] + 1e-8f);
  __syncthreads();
  float demod = red[4];
  #pragma unroll
  for (int k = 0; k < 9; ++k) {
    Wb[(((size_t)b * 9 + k) * COUT + co) * CIN + ci] = bf16r(v[k] * demod);
  }
}

// ---------------- K3: x fp32 [b][ci][h][w] -> bf16 transposed padded -----------------
// xTp[b][hh][pxp][ci]: hh in [0,130) = image row h+1 (hh=0 and hh=129 are zero guard
// rows); pxp in [0,130): pxp==0 and pxp==129 are zero pad columns, pxp=1+w.
__global__ void k_xt(const float* __restrict__ x, u16* __restrict__ xTp) {
  __shared__ u16 T[128 * 65];
  int bid = blockIdx.x;
  int b = bid >> 7, h = bid & 127;
  int t = threadIdx.x;
  size_t rowbase = ((size_t)b * 130 + (h + 1)) * 130 * CIN;
  // zero pad columns
  xTp[rowbase + t] = 0;
  xTp[rowbase + (size_t)129 * CIN + t] = 0;
  // zero guard rows
  if (h == 0) {
    uint32_t* g = (uint32_t*)(xTp + (size_t)b * 130 * 130 * CIN);
    for (int i = t; i < 130 * CIN / 2; i += 256) g[i] = 0;
  }
  if (h == 127) {
    uint32_t* g = (uint32_t*)(xTp + ((size_t)b * 130 + 129) * 130 * CIN);
    for (int i = t; i < 130 * CIN / 2; i += 256) g[i] = 0;
  }
  for (int ci0 = 0; ci0 < CIN; ci0 += 64) {
    __syncthreads();
    #pragma unroll
    for (int i = 0; i < 8; ++i) {
      int idx = t + i * 256;
      int ci = idx >> 5, px4 = idx & 31;
      float4 v = *(const float4*)(x + (((size_t)b * CIN + ci0 + ci) * HW + h) * HW + px4 * 4);
      T[(px4 * 4 + 0) * 65 + ci] = bf16r(v.x);
      T[(px4 * 4 + 1) * 65 + ci] = bf16r(v.y);
      T[(px4 * 4 + 2) * 65 + ci] = bf16r(v.z);
      T[(px4 * 4 + 3) * 65 + ci] = bf16r(v.w);
    }
    __syncthreads();
    int ci = t & 63, pxo = t >> 6;
    #pragma unroll
    for (int i = 0; i < 32; ++i) {
      int px = i * 4 + pxo;
      xTp[rowbase + (size_t)(px + 1) * CIN + ci0 + ci] = T[px * 65 + ci];
    }
  }
}

// ---------------- K4: implicit GEMM conv, 256x256 tile, LDS-free direct-feed --------
// block = (b, hp): out tile 256co x 256px (rows 2hp, 2hp+1). 8 waves 2Mx4N, wave out
// 128x64. K = 9 kpos x 256 ci = 36 K-tiles of 64, processed as 72 half-tiles (K=32).
// Operands load DIRECTLY global->VGPR (fragment pattern == memory layout); A panel
// (32KB/kt) served by L1 across 4 sharing waves, B by L1/L2. No LDS, no barriers:
// waves free-run, compiler emits counted vmcnt (MFMA of half h waits while half h+1's
// 12 loads remain in flight -> ~1240 cyc prefetch cover vs ~900 cyc HBM latency).
__global__ __launch_bounds__(512, 1) void k_conv(const u16* __restrict__ Wb,
                                                 const u16* __restrict__ xTp,
                                                 const float* __restrict__ bias,
                                                 float* __restrict__ out) {
  int bid = blockIdx.x;
  // T1: bijective XCD swizzle (nwg=1024, 1024%8==0); groups same-b blocks per XCD
  int swz = (bid & 7) * 128 + (bid >> 3);
  int b = swz >> 6, hp = swz & 63;
  int h0 = hp * 2;

  int t = threadIdx.x, lane = t & 63, wid = t >> 6;
  int wr = wid >> 2, wc = wid & 3;
  int l15 = lane & 15, seg = lane >> 4;

  const u16* Ab = Wb + (size_t)b * 9 * 65536;
  const u16* Bb = xTp + (size_t)b * 130 * 130 * 256;

  // per-lane invariant address parts (elements)
  int aoff = (wr * 128 + l15) * 256 + seg * 8;        // + mt*4096 + uniform(kpos,ci0,kk)
  int boff = ((wc & 1) * 64 + l15) * 256 + seg * 8;   // + nt*4096 + uniform
  int hrow = h0 + (wc >> 1);                          // + kh (wave-uniform)

  f32x4 acc[8][4];
  #pragma unroll
  for (int i = 0; i < 8; ++i)
    #pragma unroll
    for (int j = 0; j < 4; ++j) acc[i][j] = (f32x4)0.f;

  short8 cA[8], cB[4], nA[8], nB[4];

  // half-tile ht = 0..71: kt = ht>>1 (kpos = kt>>2, ci0 = (kt&3)*64), kk = ht&1
#define LOADA(DST, HT)                                                          \
  do {                                                                          \
    int kt_ = (HT) >> 1, kk_ = (HT) & 1;                                        \
    int kpos_ = kt_ >> 2, ci0_ = (kt_ & 3) << 6;                                \
    const u16* p_ = Ab + kpos_ * 65536 + ci0_ + kk_ * 32 + aoff;                \
    _Pragma("unroll")                                                           \
    for (int mt = 0; mt < 8; ++mt) DST[mt] = *(const short8*)(p_ + mt * 4096);  \
  } while (0)
#define LOADB(DST, HT)                                                          \
  do {                                                                          \
    int kt_ = (HT) >> 1, kk_ = (HT) & 1;                                        \
    int kpos_ = kt_ >> 2, ci0_ = (kt_ & 3) << 6;                                \
    int kh_ = kpos_ < 3 ? 0 : (kpos_ < 6 ? 1 : 2);                              \
    int kw_ = kpos_ - kh_ * 3;                                                  \
    const u16* p_ = Bb + ((size_t)(hrow + kh_) * 130 + kw_) * 256               \
                       + ci0_ + kk_ * 32 + boff;                                \
    _Pragma("unroll")                                                           \
    for (int nt = 0; nt < 4; ++nt) DST[nt] = *(const short8*)(p_ + nt * 4096);  \
  } while (0)
#define MF(SA, SB)                                                              \
  _Pragma("unroll")                                                             \
  for (int mt = 0; mt < 8; ++mt)                                                \
    _Pragma("unroll")                                                           \
    for (int nt = 0; nt < 4; ++nt)                                              \
      acc[mt][nt] =                                                             \
          __builtin_amdgcn_mfma_f32_16x16x32_bf16(SA[mt], SB[nt], acc[mt][nt], 0, 0, 0);

  LOADA(cA, 0);
  LOADB(cB, 0);
  #pragma unroll 1
  for (int ht = 0; ht < 72; ht += 2) {
    // issue next-half loads, then consume current (compiler waits only cur's loads)
    LOADA(nA, ht + 1);
    LOADB(nB, ht + 1);
    MF(cA, cB);
    if (ht + 2 < 72) {
      LOADA(cA, ht + 2);
      LOADB(cB, ht + 2);
    }
    MF(nA, nB);
  }
#undef LOADA
#undef LOADB
#undef MF

  // -------- epilogue: C write --------
  #pragma unroll
  for (int mt = 0; mt < 8; ++mt) {
    #pragma unroll
    for (int j = 0; j < 4; ++j) {
      int co = wr * 128 + mt * 16 + ((lane >> 4) * 4) + j;
      float bv = bias[co];
      #pragma unroll
      for (int nt = 0; nt < 4; ++nt) {
        int px = wc * 64 + nt * 16 + l15;
        int h = h0 + (px >> 7), w = px & 127;
        out[(((size_t)b * COUT + co) * HW + h) * HW + w] = acc[mt][nt][j] + bv;
      }
    }
  }
}

extern "C" void kernel_launch(void* const* d_in, const int* in_sizes, int n_in,
                              void* d_out, int out_size, void* d_ws, size_t ws_size,
                              hipStream_t stream) {
  const float* x      = (const float*)d_in[0];
  const float* style  = (const float*)d_in[1];
  const float* weight = (const float*)d_in[2];
  const float* mod_w  = (const float*)d_in[3];
  const float* mod_b  = (const float*)d_in[4];
  const float* bias   = (const float*)d_in[5];
  float* out = (float*)d_out;

  char* ws = (char*)d_ws;
  float* s   = (float*)ws;                                           // 16 KB
  u16* Wb    = (u16*)(ws + 16384);                                   // 18.9 MB
  u16* xTp   = (u16*)(ws + 16384 + (size_t)NB * 9 * COUT * CIN * 2); // 138.4 MB

  k_style<<<NB, 256, 0, stream>>>(style, mod_w, mod_b, s);
  k_wmod<<<NB * COUT, 256, 0, stream>>>(weight, s, Wb);
  k_xt<<<NB * HW, 256, 0, stream>>>(x, xTp);
  k_conv<<<NB * (HW / 2), 512, 0, stream>>>(Wb, xTp, bias, out);
}

// Round 8
// 722.494 us; speedup vs baseline: 1.2713x; 1.2713x over previous
//
#include <hip/hip_runtime.h>
#include <stdint.h>

typedef unsigned short u16;
typedef __attribute__((ext_vector_type(8))) short short8;
typedef __attribute__((ext_vector_type(16))) float f32x16;

#define AS1 __attribute__((address_space(1)))
#define AS3 __attribute__((address_space(3)))

static __device__ __forceinline__ void gload_lds16(const void* g, void* l) {
  __builtin_amdgcn_global_load_lds((const AS1 void*)g, (AS3 void*)l, 16, 0, 0);
}

static __device__ __forceinline__ u16 bf16r(float f) {
  union { float f; uint32_t u; } c; c.f = f;
  uint32_t u = c.u;
  u += 0x7fffu + ((u >> 16) & 1u);
  return (u16)(u >> 16);
}

static constexpr int NB = 16, CIN = 256, COUT = 256, HW = 128, SDIM = 512;
static constexpr float SCALE = 1.0f / 48.0f;   // 1/sqrt(Cin*3*3)

// ---------------- K1: s[b][ci] = style[b,:] @ mod_w[ci,:] + mod_b[ci] ----------------
__global__ void k_style(const float* __restrict__ style, const float* __restrict__ mod_w,
                        const float* __restrict__ mod_b, float* __restrict__ s) {
  int b = blockIdx.x, ci = threadIdx.x;
  const float4* st = (const float4*)(style + (size_t)b * SDIM);
  const float4* mw = (const float4*)(mod_w + (size_t)ci * SDIM);
  float acc = 0.f;
  #pragma unroll 4
  for (int j = 0; j < SDIM / 4; ++j) {
    float4 a = st[j], w = mw[j];
    acc += a.x * w.x + a.y * w.y + a.z * w.z + a.w * w.w;
  }
  s[b * CIN + ci] = acc + mod_b[ci];
}

// ---------------- K2: modulated+demodulated weights -> bf16 Wb[b][kpos][co][ci] ------
__global__ void k_wmod(const float* __restrict__ weight, const float* __restrict__ s,
                       u16* __restrict__ Wb) {
  __shared__ float wld[CIN * 9];
  __shared__ float red[8];
  int bid = blockIdx.x;
  int b = bid >> 8, co = bid & 255;
  int t = threadIdx.x;
  const float* wsrc = weight + (size_t)co * (CIN * 9);
  for (int i = t; i < CIN * 9; i += 256) wld[i] = wsrc[i];
  __syncthreads();
  int ci = t;
  float sv = s[b * CIN + ci];
  float v[9];
  float sq = 0.f;
  #pragma unroll
  for (int k = 0; k < 9; ++k) {
    float w = SCALE * wld[ci * 9 + k] * sv;
    v[k] = w;
    sq += w * w;
  }
  #pragma unroll
  for (int off = 32; off; off >>= 1) sq += __shfl_down(sq, off);
  int lane = t & 63, wid = t >> 6;
  if (lane == 0) red[wid] = sq;
  __syncthreads();
  if (t == 0) red[4] = rsqrtf(red[0] + red[1] + red[2] + red[3] + 1e-8f);
  __syncthreads();
  float demod = red[4];
  #pragma unroll
  for (int k = 0; k < 9; ++k) {
    Wb[(((size_t)b * 9 + k) * COUT + co) * CIN + ci] = bf16r(v[k] * demod);
  }
}

// ---------------- K3: x fp32 [b][ci][h][w] -> bf16 transposed padded -----------------
// xTp[b][hh][pxp][ci]: hh in [0,130) = image row h+1 (hh=0 and hh=129 are zero guard
// rows); pxp in [0,130): pxp==0 and pxp==129 are zero pad columns, pxp=1+w.
__global__ void k_xt(const float* __restrict__ x, u16* __restrict__ xTp) {
  __shared__ u16 T[128 * 65];
  int bid = blockIdx.x;
  int b = bid >> 7, h = bid & 127;
  int t = threadIdx.x;
  size_t rowbase = ((size_t)b * 130 + (h + 1)) * 130 * CIN;
  // zero pad columns
  xTp[rowbase + t] = 0;
  xTp[rowbase + (size_t)129 * CIN + t] = 0;
  // zero guard rows
  if (h == 0) {
    uint32_t* g = (uint32_t*)(xTp + (size_t)b * 130 * 130 * CIN);
    for (int i = t; i < 130 * CIN / 2; i += 256) g[i] = 0;
  }
  if (h == 127) {
    uint32_t* g = (uint32_t*)(xTp + ((size_t)b * 130 + 129) * 130 * CIN);
    for (int i = t; i < 130 * CIN / 2; i += 256) g[i] = 0;
  }
  for (int ci0 = 0; ci0 < CIN; ci0 += 64) {
    __syncthreads();
    #pragma unroll
    for (int i = 0; i < 8; ++i) {
      int idx = t + i * 256;
      int ci = idx >> 5, px4 = idx & 31;
      float4 v = *(const float4*)(x + (((size_t)b * CIN + ci0 + ci) * HW + h) * HW + px4 * 4);
      T[(px4 * 4 + 0) * 65 + ci] = bf16r(v.x);
      T[(px4 * 4 + 1) * 65 + ci] = bf16r(v.y);
      T[(px4 * 4 + 2) * 65 + ci] = bf16r(v.z);
      T[(px4 * 4 + 3) * 65 + ci] = bf16r(v.w);
    }
    __syncthreads();
    int ci = t & 63, pxo = t >> 6;
    #pragma unroll
    for (int i = 0; i < 32; ++i) {
      int px = i * 4 + pxo;
      xTp[rowbase + (size_t)(px + 1) * CIN + ci0 + ci] = T[px * 65 + ci];
    }
  }
}

// ---------------- K4: implicit GEMM conv: A direct from L2, B via LDS, 32x32 MFMA ---
// block = (b, hp): out 256co x 256px (rows 2hp,2hp+1). 8 waves 2Mx4N, wave 128x64.
// K = 36 K-tiles of 64 = 4 ksteps of 16 each. A fragments load straight from Wb
// (pattern matches memory; panel 32KB/kt is L1/L2-resident), 2-kstep rolling window,
// next-kt A issued BEFORE the barrier. B staged via gload_lds (swizzled, dbuf),
// one __syncthreads per kt.
static constexpr int BSLOT = 16384;  // u16 per B slot (256 rows x 64)

__global__ __launch_bounds__(512, 2) void k_conv(const u16* __restrict__ Wb,
                                                 const u16* __restrict__ xTp,
                                                 const float* __restrict__ bias,
                                                 float* __restrict__ out) {
  extern __shared__ u16 lds[];
  int bid = blockIdx.x;
  // T1: bijective XCD swizzle (nwg=1024, 1024%8==0)
  int swz = (bid & 7) * 128 + (bid >> 3);
  int b = swz >> 6, hp = swz & 63;
  int h0 = hp * 2;

  int t = threadIdx.x, lane = t & 63, wid = t >> 6;
  int wr = wid >> 2, wc = wid & 3;
  int l31 = lane & 31, l7 = lane & 7, seg = lane >> 5;

  const u16* Ab = Wb + (size_t)b * 9 * 65536;
  const u16* Bb = xTp + (size_t)b * 130 * 130 * 256;

  int aRow = wr * 128 + l31;                 // + mt*32
  // B LDS read: px row = wc*64 + nt*32 + l31; unit = (kstep*2+seg) ^ (px&7)=l7
  int bro = (wc * 64 + l31) * 64;            // + nt*2048 ; + ((ks*2+seg)^l7)*8
  // stage-side
  int srow8 = lane >> 3;
  int ssrc = (l7 ^ srow8) * 8;               // pre-swizzled source unit

  f32x16 acc[4][2];
  #pragma unroll
  for (int i = 0; i < 4; ++i)
    #pragma unroll
    for (int j = 0; j < 2; ++j) acc[i][j] = (f32x16)0.f;

#define LOADA(DST, KT, KS)                                                       \
  do {                                                                           \
    int kpos_ = (KT) >> 2, ci0_ = ((KT) & 3) << 6;                               \
    const u16* p_ = Ab + kpos_ * 65536 + (size_t)aRow * 256 + ci0_               \
                    + (KS) * 16 + seg * 8;                                       \
    _Pragma("unroll")                                                            \
    for (int mt = 0; mt < 4; ++mt) DST[mt] = *(const short8*)(p_ + mt * 8192);   \
  } while (0)

#define LDB(KS)                                                                  \
  do {                                                                           \
    bq[0] = *(const short8*)&S[bro + 0 * 2048 + ((((KS) * 2 + seg) ^ l7) * 8)];  \
    bq[1] = *(const short8*)&S[bro + 1 * 2048 + ((((KS) * 2 + seg) ^ l7) * 8)];  \
  } while (0)

#define STAGEB(KT)                                                               \
  do {                                                                           \
    int kpos_ = (KT) >> 2, ci0_ = ((KT) & 3) << 6;                               \
    int kh_ = kpos_ < 3 ? 0 : (kpos_ < 6 ? 1 : 2);                               \
    int kw_ = kpos_ - kh_ * 3;                                                   \
    u16* d_ = lds + ((KT) & 1) * BSLOT;                                          \
    _Pragma("unroll")                                                            \
    for (int i = 0; i < 4; ++i) {                                                \
      int r_ = i * 64 + wid * 8 + srow8;                                         \
      const u16* s_ = Bb + ((size_t)(h0 + kh_ + (r_ >> 7)) * 130 + kw_           \
                            + (r_ & 127)) * 256 + ci0_ + ssrc;                   \
      gload_lds16(s_, d_ + (i * 64 + wid * 8) * 64);                             \
    }                                                                            \
  } while (0)

#define MFMA8(AF)                                                                \
  _Pragma("unroll")                                                              \
  for (int mt = 0; mt < 4; ++mt) {                                               \
    acc[mt][0] = __builtin_amdgcn_mfma_f32_32x32x16_bf16(AF[mt], bq[0], acc[mt][0], 0, 0, 0); \
    acc[mt][1] = __builtin_amdgcn_mfma_f32_32x32x16_bf16(AF[mt], bq[1], acc[mt][1], 0, 0, 0); \
  }

  // prologue
  STAGEB(0);
  short8 a0[4], a1[4], a2[4], a3[4], bq[2];
  LOADA(a0, 0, 0);
  LOADA(a1, 0, 1);
  __syncthreads();

  for (int kt = 0; kt < 36; ++kt) {
    const u16* S = lds + (kt & 1) * BSLOT;
    bool pf = kt + 1 < 36;
    LDB(0);
    LOADA(a2, kt, 2);
    MFMA8(a0);
    LDB(1);
    LOADA(a3, kt, 3);
    MFMA8(a1);
    if (pf) STAGEB(kt + 1);
    LDB(2);
    if (pf) {
      LOADA(a0, kt + 1, 0);       // global-only: legally spans the barrier
      LOADA(a1, kt + 1, 1);
    }
    MFMA8(a2);
    LDB(3);
    MFMA8(a3);
    __syncthreads();
  }
#undef LOADA
#undef LDB
#undef STAGEB
#undef MFMA8

  // -------- epilogue: C write (32x32 layout: col=lane&31, row=(j&3)+8*(j>>2)+4*seg) --
  #pragma unroll
  for (int mt = 0; mt < 4; ++mt) {
    #pragma unroll
    for (int nt = 0; nt < 2; ++nt) {
      int px = wc * 64 + nt * 32 + l31;
      int h = h0 + (px >> 7), w = px & 127;
      #pragma unroll
      for (int j = 0; j < 16; ++j) {
        int co = wr * 128 + mt * 32 + (j & 3) + 8 * (j >> 2) + 4 * seg;
        out[(((size_t)b * COUT + co) * HW + h) * HW + w] = acc[mt][nt][j] + bias[co];
      }
    }
  }
}

extern "C" void kernel_launch(void* const* d_in, const int* in_sizes, int n_in,
                              void* d_out, int out_size, void* d_ws, size_t ws_size,
                              hipStream_t stream) {
  const float* x      = (const float*)d_in[0];
  const float* style  = (const float*)d_in[1];
  const float* weight = (const float*)d_in[2];
  const float* mod_w  = (const float*)d_in[3];
  const float* mod_b  = (const float*)d_in[4];
  const float* bias   = (const float*)d_in[5];
  float* out = (float*)d_out;

  char* ws = (char*)d_ws;
  float* s   = (float*)ws;                                           // 16 KB
  u16* Wb    = (u16*)(ws + 16384);                                   // 18.9 MB
  u16* xTp   = (u16*)(ws + 16384 + (size_t)NB * 9 * COUT * CIN * 2); // 138.4 MB

  (void)hipFuncSetAttribute((const void*)k_conv,
                            hipFuncAttributeMaxDynamicSharedMemorySize, 2 * BSLOT * 2);

  k_style<<<NB, 256, 0, stream>>>(style, mod_w, mod_b, s);
  k_wmod<<<NB * COUT, 256, 0, stream>>>(weight, s, Wb);
  k_xt<<<NB * HW, 256, 0, stream>>>(x, xTp);
  k_conv<<<NB * (HW / 2), 512, 2 * BSLOT * 2, stream>>>(Wb, xTp, bias, out);
}